// Round 1
// baseline (261.710 us; speedup 1.0000x reference)
//
#include <hip/hip_runtime.h>
#include <hip/hip_bf16.h>
#include <stdint.h>

// B=2, T=2048, D=1024, H=16, HD=64, SCALE=1/8. Softmax is over the HEAD axis.
typedef __bf16 bf16;
typedef __attribute__((ext_vector_type(8))) __bf16 bf16x8;
typedef __attribute__((ext_vector_type(4))) float f32x4;

#define MFMA_16x16x32(a, b, c) __builtin_amdgcn_mfma_f32_16x16x32_bf16((a), (b), (c), 0, 0, 0)

__device__ __forceinline__ void gld_lds16(const void* g, void* l) {
    __builtin_amdgcn_global_load_lds(
        (const __attribute__((address_space(1))) void*)g,
        (__attribute__((address_space(3))) void*)l,
        16, 0, 0);
}

// ---------- fp32 -> bf16 convert (vectorized) ----------
__global__ void cvt_f32_bf16(const float* __restrict__ in, bf16* __restrict__ out, int n) {
    int i = (blockIdx.x * blockDim.x + threadIdx.x) * 8;
    if (i >= n) return;
    f32x4 a = *(const f32x4*)(in + i);
    f32x4 b = *(const f32x4*)(in + i + 4);
    bf16x8 o;
#pragma unroll
    for (int j = 0; j < 4; ++j) { o[j] = (bf16)a[j]; o[j + 4] = (bf16)b[j]; }
    *(bf16x8*)(out + i) = o;
}

// ---------- transpose + convert: in[R][C] f32 -> out[C][R] bf16 ----------
__global__ void transpose_cvt(const float* __restrict__ in, bf16* __restrict__ out, int R, int C) {
    __shared__ float tile[32][33];
    int c0 = blockIdx.x * 32, r0 = blockIdx.y * 32;
    int tc = threadIdx.x & 31, tr = threadIdx.x >> 5; // tr in 0..7
#pragma unroll
    for (int i = 0; i < 4; ++i) {
        int r = tr + i * 8;
        tile[r][tc] = in[(size_t)(r0 + r) * C + c0 + tc];
    }
    __syncthreads();
#pragma unroll
    for (int i = 0; i < 4; ++i) {
        int r = tr + i * 8; // out row = original column
        out[(size_t)(c0 + r) * R + r0 + tc] = (bf16)tile[tc][r];
    }
}

// ---------- bf16 GEMM, C = A[M,K] @ Bt[N,K]^T ; 128x128 tile, BK=32, 4 waves ----------
// EPI==0: scatter-store qkv -> q[B,H,T,HD], k[B,H,T,HD], v^T[B,H,HD,T]  (all bf16)
// EPI==1: fp32 store + bias
template <int EPI>
__global__ void __launch_bounds__(256) gemm_bf16(
    const bf16* __restrict__ A, const bf16* __restrict__ Bt, int M, int N, int K,
    float* __restrict__ Cf, const float* __restrict__ bias,
    bf16* __restrict__ q_out, bf16* __restrict__ k_out, bf16* __restrict__ v_out)
{
    __shared__ bf16 As[128 * 32];
    __shared__ bf16 Bs[128 * 32];
    const int t = threadIdx.x, w = t >> 6, l = t & 63;
    const int l15 = l & 15, lh = l >> 4;
    const int m0 = blockIdx.y * 128, n0 = blockIdx.x * 128;
    const int wm = w >> 1, wn = w & 1;

    // staging: thread t -> LDS byte t*16 (wave-uniform base + lane*16 by HW)
    const int srow = w * 16 + (l >> 2);
    const int scol = (l & 3) * 8;
    const bf16* gA = A + (size_t)(m0 + srow) * K + scol;
    const bf16* gB = Bt + (size_t)(n0 + srow) * K + scol;
    char* lA = (char*)As + w * 1024;
    char* lB = (char*)Bs + w * 1024;

    f32x4 acc[4][4] = {};

    for (int kt = 0; kt < K; kt += 32) {
        __syncthreads();
        gld_lds16(gA + kt, lA);
        gld_lds16(gA + (size_t)64 * K + kt, lA + 4096);
        gld_lds16(gB + kt, lB);
        gld_lds16(gB + (size_t)64 * K + kt, lB + 4096);
        asm volatile("s_waitcnt vmcnt(0)" ::: "memory");
        __syncthreads();

        const bf16* pa = As + (wm * 64 + l15) * 32 + lh * 8;
        const bf16* pb = Bs + (wn * 64 + l15) * 32 + lh * 8;
        bf16x8 af[4], bfr[4];
#pragma unroll
        for (int i = 0; i < 4; ++i) {
            af[i]  = *(const bf16x8*)(pa + i * 512);
            bfr[i] = *(const bf16x8*)(pb + i * 512);
        }
#pragma unroll
        for (int mi = 0; mi < 4; ++mi)
#pragma unroll
            for (int ni = 0; ni < 4; ++ni)
                acc[mi][ni] = MFMA_16x16x32(af[mi], bfr[ni], acc[mi][ni]);
    }

    if (EPI == 1) {
#pragma unroll
        for (int ni = 0; ni < 4; ++ni) {
            int n = n0 + wn * 64 + ni * 16 + l15;
            float bb = bias[n];
#pragma unroll
            for (int mi = 0; mi < 4; ++mi)
#pragma unroll
                for (int r = 0; r < 4; ++r) {
                    int m = m0 + wm * 64 + mi * 16 + lh * 4 + r;
                    Cf[(size_t)m * N + n] = acc[mi][ni][r] + bb;
                }
        }
    } else {
        const int which = n0 >> 10; // 0:q 1:k 2:v — uniform per block (128 | 1024)
#pragma unroll
        for (int ni = 0; ni < 4; ++ni) {
            int n = n0 + wn * 64 + ni * 16 + l15;
            int h = (n >> 6) & 15;
            int d = n & 63;
#pragma unroll
            for (int mi = 0; mi < 4; ++mi)
#pragma unroll
                for (int r = 0; r < 4; ++r) {
                    int m = m0 + wm * 64 + mi * 16 + lh * 4 + r;
                    int b = m >> 11, tt = m & 2047;
                    bf16 val = (bf16)acc[mi][ni][r];
                    size_t hb = (size_t)b * 16 + h;
                    if (which == 0)      q_out[(hb * 2048 + tt) * 64 + d] = val;
                    else if (which == 1) k_out[(hb * 2048 + tt) * 64 + d] = val;
                    else                 v_out[(hb * 64 + d) * 2048 + tt] = val;
                }
        }
    }
}

// ---------- attention with head-axis softmax ----------
// grid 256 = B(2) x kslice(2) x qtile(64); 1024 threads = 16 waves, wave w = head w.
// QB=32 q-rows, KB=32 k-rows per iter, k-slice of 1024 rows per block.
__global__ void __launch_bounds__(1024) attn_kernel(
    const bf16* __restrict__ Q, const bf16* __restrict__ Kmat, const bf16* __restrict__ Vt,
    bf16* __restrict__ part)
{
    __shared__ bf16 S[16][32][40]; // [head][q][k] bf16, pad 40 keeps 16B align, spreads banks
    const int t = threadIdx.x;
    const int w = t >> 6;       // head
    const int l = t & 63;
    const int l15 = l & 15, lh = l >> 4;

    const int bi = blockIdx.x;
    const int qtile = bi & 63;
    const int kslice = (bi >> 6) & 1;
    const int b = bi >> 7;
    const int qt = qtile * 32;

    const size_t headQK = ((size_t)b * 16 + w) * (2048 * 64); // [B,H,T,HD]
    const size_t headV  = ((size_t)b * 16 + w) * (64 * 2048); // [B,H,HD,T]

    // Q fragments live in registers for the whole block
    bf16x8 aq[2][2];
#pragma unroll
    for (int qb2 = 0; qb2 < 2; ++qb2)
#pragma unroll
        for (int ds = 0; ds < 2; ++ds)
            aq[qb2][ds] = *(const bf16x8*)(Q + headQK + (size_t)(qt + qb2 * 16 + l15) * 64 + ds * 32 + lh * 8);

    f32x4 o[2][4] = {};
    const int qi = t >> 5, ki = t & 31; // softmax ownership: one (q,k) column per thread

    for (int it = 0; it < 32; ++it) {
        const int kt = kslice * 1024 + it * 32;
        __syncthreads(); // protect S from previous iteration's PV reads
        // --- scores S[h][q][k] = (Q.K^T)*1/8 ---
#pragma unroll
        for (int kb = 0; kb < 2; ++kb) {
            const bf16* kp = Kmat + headQK + (size_t)(kt + kb * 16 + l15) * 64 + lh * 8;
            bf16x8 bk0 = *(const bf16x8*)(kp);
            bf16x8 bk1 = *(const bf16x8*)(kp + 32);
#pragma unroll
            for (int qb2 = 0; qb2 < 2; ++qb2) {
                f32x4 s = {};
                s = MFMA_16x16x32(aq[qb2][0], bk0, s);
                s = MFMA_16x16x32(aq[qb2][1], bk1, s);
#pragma unroll
                for (int r = 0; r < 4; ++r)
                    S[w][qb2 * 16 + lh * 4 + r][kb * 16 + l15] = (bf16)(s[r] * 0.125f);
            }
        }
        __syncthreads();
        // --- softmax over the 16 heads; exact, in-place (each thread owns its column) ---
        {
            float sh[16];
            float mx = -1e30f;
#pragma unroll
            for (int hh = 0; hh < 16; ++hh) { sh[hh] = (float)S[hh][qi][ki]; mx = fmaxf(mx, sh[hh]); }
            float sum = 0.f;
#pragma unroll
            for (int hh = 0; hh < 16; ++hh) { float e = __expf(sh[hh] - mx); sh[hh] = e; sum += e; }
            float inv = 1.f / sum;
#pragma unroll
            for (int hh = 0; hh < 16; ++hh) S[hh][qi][ki] = (bf16)(sh[hh] * inv);
        }
        __syncthreads();
        // --- PV: o += P @ V (V read k-contiguous thanks to transposed layout) ---
        bf16x8 bv[4];
#pragma unroll
        for (int ni = 0; ni < 4; ++ni)
            bv[ni] = *(const bf16x8*)(Vt + headV + (size_t)(ni * 16 + l15) * 2048 + kt + lh * 8);
#pragma unroll
        for (int qb2 = 0; qb2 < 2; ++qb2) {
            bf16x8 ap = *(const bf16x8*)(&S[w][qb2 * 16 + l15][lh * 8]);
#pragma unroll
            for (int ni = 0; ni < 4; ++ni)
                o[qb2][ni] = MFMA_16x16x32(ap, bv[ni], o[qb2][ni]);
        }
    }
    // write this k-slice's partial: part[kslice][b][t][h*64+d]
    bf16* dst = part + (size_t)(kslice * 2 + b) * (2048 * 1024);
#pragma unroll
    for (int qb2 = 0; qb2 < 2; ++qb2)
#pragma unroll
        for (int ni = 0; ni < 4; ++ni)
#pragma unroll
            for (int r = 0; r < 4; ++r) {
                int tt = qt + qb2 * 16 + lh * 4 + r;
                int d = ni * 16 + l15;
                dst[(size_t)tt * 1024 + w * 64 + d] = (bf16)o[qb2][ni][r];
            }
}

// ---------- sum the two k-slice partials -> attn bf16 ----------
__global__ void reduce_part(const bf16* __restrict__ part, bf16* __restrict__ out, int n) {
    int i = (blockIdx.x * blockDim.x + threadIdx.x) * 8;
    if (i >= n) return;
    bf16x8 a = *(const bf16x8*)(part + i);
    bf16x8 b = *(const bf16x8*)(part + n + i);
    bf16x8 o;
#pragma unroll
    for (int j = 0; j < 8; ++j) o[j] = (bf16)((float)a[j] + (float)b[j]);
    *(bf16x8*)(out + i) = o;
}

extern "C" void kernel_launch(void* const* d_in, const int* in_sizes, int n_in,
                              void* d_out, int out_size, void* d_ws, size_t ws_size,
                              hipStream_t stream)
{
    const float* x      = (const float*)d_in[0];
    const float* w_qkv  = (const float*)d_in[1];
    const float* w_proj = (const float*)d_in[2];
    const float* b_proj = (const float*)d_in[3];
    float* out = (float*)d_out;

    // workspace layout (64 MiB total)
    char* ws = (char*)d_ws;
    bf16* xb     = (bf16*)(ws + 0);         //  8 MiB  x as bf16        [4096,1024]
    bf16* wqkvT  = (bf16*)(ws + 8388608);   //  6 MiB  w_qkv^T bf16     [3072,1024]
    bf16* wprojT = (bf16*)(ws + 14680064);  //  2 MiB  w_proj^T bf16    [1024,1024]
    bf16* qb     = (bf16*)(ws + 16777216);  //  8 MiB  Q  [B,H,T,HD]
    bf16* kb     = (bf16*)(ws + 25165824);  //  8 MiB  K  [B,H,T,HD]
    bf16* vt     = (bf16*)(ws + 33554432);  //  8 MiB  V^T[B,H,HD,T]
    bf16* part   = (bf16*)(ws + 41943040);  // 16 MiB  attn partials [2][B,T,D]
    bf16* attnb  = (bf16*)(ws + 58720256);  //  8 MiB  attn_out bf16 [4096,1024]

    cvt_f32_bf16<<<2048, 256, 0, stream>>>(x, xb, 4194304);
    transpose_cvt<<<dim3(96, 32), 256, 0, stream>>>(w_qkv, wqkvT, 1024, 3072);
    transpose_cvt<<<dim3(32, 32), 256, 0, stream>>>(w_proj, wprojT, 1024, 1024);

    // qkv projection: [4096,1024] @ [1024,3072] -> scatter to q/k/v^T
    gemm_bf16<0><<<dim3(24, 32), 256, 0, stream>>>(xb, wqkvT, 4096, 3072, 1024,
                                                   nullptr, nullptr, qb, kb, vt);
    // attention with head-axis softmax (2 k-slices)
    attn_kernel<<<256, 1024, 0, stream>>>(qb, kb, vt, part);
    reduce_part<<<2048, 256, 0, stream>>>(part, attnb, 4194304);
    // output projection + bias -> fp32 d_out
    gemm_bf16<1><<<dim3(8, 32), 256, 0, stream>>>(attnb, wprojT, 4096, 1024, 1024,
                                                  out, b_proj, nullptr, nullptr, nullptr);

    (void)in_sizes; (void)n_in; (void)out_size; (void)ws_size;
}